// Round 6
// baseline (212.338 us; speedup 1.0000x reference)
//
#include <hip/hip_runtime.h>

typedef __bf16 bf16_t;
typedef bf16_t bf16x8 __attribute__((ext_vector_type(8)));
typedef bf16_t bf16x4 __attribute__((ext_vector_type(4)));
typedef float f32x4 __attribute__((ext_vector_type(4)));

#define KDIM 256
#define NWIN 128
#define WIN  256
#define LDS_STRIDE 264   // 256 + 8 pad
#define GEMM_LDS_BYTES (2 * 128 * LDS_STRIDE * 2)

__device__ __forceinline__ bf16x8 cvt8(f32x4 a, f32x4 b) {
    bf16x8 o;
    o[0] = (bf16_t)a[0]; o[1] = (bf16_t)a[1]; o[2] = (bf16_t)a[2]; o[3] = (bf16_t)a[3];
    o[4] = (bf16_t)b[0]; o[5] = (bf16_t)b[1]; o[6] = (bf16_t)b[2]; o[7] = (bf16_t)b[3];
    return o;
}

// Single-shot GEMM: C[M,N] = A[M,256] * B[N,256]^T (+bias, relu<relu_cols).
// Full K panel staged in LDS once (135 KB dynamic): all staging loads issued
// with no intervening dependency, ONE barrier, then 8x(8 ds_read + 16 MFMA)
// per wave with zero vmcnt(0) drains. 1 block/CU.
template<int A_FP32, int F32OUT>
__global__ __launch_bounds__(256) void gemm_os(
    const void* __restrict__ A_,
    const float* __restrict__ Bw,
    void* __restrict__ Cout,
    int N,
    const float* __restrict__ bias,
    int relu_cols)
{
    extern __shared__ __align__(16) bf16_t lds[];
    bf16_t* As = lds;                        // [128][264]
    bf16_t* Bs = lds + 128 * LDS_STRIDE;     // [128][264]

    const int tid = threadIdx.x;
    const int m0 = blockIdx.x * 128;
    const int n0 = blockIdx.y * 128;

    // Staging: thread -> (row = tid>>1, col half = (tid&1)*128)
    const int srow = tid >> 1;
    const int sh   = (tid & 1) * 128;

    if (A_FP32) {
        const float* ap = (const float*)A_ + (size_t)(m0 + srow) * KDIM + sh;
#pragma unroll
        for (int u = 0; u < 16; ++u) {
            f32x4 f0 = *(const f32x4*)(ap + u * 8);
            f32x4 f1 = *(const f32x4*)(ap + u * 8 + 4);
            *(bf16x8*)(&As[srow * LDS_STRIDE + sh + u * 8]) = cvt8(f0, f1);
        }
    } else {
        const bf16_t* ap = (const bf16_t*)A_ + (size_t)(m0 + srow) * KDIM + sh;
#pragma unroll
        for (int u = 0; u < 16; ++u)
            *(bf16x8*)(&As[srow * LDS_STRIDE + sh + u * 8]) = *(const bf16x8*)(ap + u * 8);
    }
    {
        const float* bp = Bw + (size_t)(n0 + srow) * KDIM + sh;
#pragma unroll
        for (int u = 0; u < 16; ++u) {
            f32x4 f0 = *(const f32x4*)(bp + u * 8);
            f32x4 f1 = *(const f32x4*)(bp + u * 8 + 4);
            *(bf16x8*)(&Bs[srow * LDS_STRIDE + sh + u * 8]) = cvt8(f0, f1);
        }
    }
    __syncthreads();

    const int lane = tid & 63;
    const int wv = tid >> 6;
    const int wm = wv >> 1, wn = wv & 1;
    const int r = lane & 15, q = lane >> 4;

    f32x4 acc[4][4] = {};
#pragma unroll
    for (int kc = 0; kc < KDIM; kc += 32) {
        bf16x8 a[4], b[4];
#pragma unroll
        for (int i = 0; i < 4; ++i)
            a[i] = *(const bf16x8*)(&As[(wm * 64 + i * 16 + r) * LDS_STRIDE + kc + q * 8]);
#pragma unroll
        for (int j = 0; j < 4; ++j)
            b[j] = *(const bf16x8*)(&Bs[(wn * 64 + j * 16 + r) * LDS_STRIDE + kc + q * 8]);
#pragma unroll
        for (int i = 0; i < 4; ++i)
#pragma unroll
            for (int j = 0; j < 4; ++j)
                acc[i][j] = __builtin_amdgcn_mfma_f32_16x16x32_bf16(a[i], b[j], acc[i][j], 0, 0, 0);
    }

#pragma unroll
    for (int i = 0; i < 4; ++i) {
#pragma unroll
        for (int j = 0; j < 4; ++j) {
            const int colg = n0 + wn * 64 + j * 16 + r;
            float badd = bias ? bias[colg] : 0.0f;
#pragma unroll
            for (int reg = 0; reg < 4; ++reg) {
                const int rowg = m0 + wm * 64 + i * 16 + q * 4 + reg;
                float v = acc[i][j][reg] + badd;
                if (colg < relu_cols) v = fmaxf(v, 0.0f);
                const size_t idx = (size_t)rowg * N + colg;
                if (F32OUT) ((float*)Cout)[idx] = v;
                else        ((bf16_t*)Cout)[idx] = (bf16_t)v;
            }
        }
    }
}

// Fused per-(window,head) linear attention (verified in R5, unchanged):
//   KV[c][d] = sum_t k[t][c] v[t][d]; s[c] = sum_t k[t][c];
//   y[t][d]  = (q[t].KV[:,d]) / (q[t].s + eps)
__global__ __launch_bounds__(256) void kvy_kernel(
    const bf16_t* __restrict__ QKV,   // [Ntok, 768]
    const int* __restrict__ offsets,
    const int* __restrict__ counts,
    bf16_t* __restrict__ Y)           // [Ntok, 256]
{
    const int w = blockIdx.x;
    const int h = blockIdx.y;
    const int is64 = (counts[1] == 0) ? 1 : 0;
    const int off = offsets[w << is64];
    const int tid = threadIdx.x;
    const int lane = tid & 63;
    const int wv = tid >> 6;

    __shared__ __align__(16) bf16_t KT[32 * 264];
    __shared__ __align__(16) bf16_t VT[32 * 264];
    __shared__ __align__(16) bf16_t KVT[32 * 40];
    __shared__ float sbuf[32];
    __shared__ float spart[32 * 8];
    __shared__ float zinv[WIN];

    {
        const int t = tid;
        const bf16_t* kp = QKV + (size_t)(off + t) * 768 + 256 + h * 32;
        const bf16_t* vp = kp + 256;
        bf16_t ka[32], va[32];
#pragma unroll
        for (int u = 0; u < 4; ++u) {
            bf16x8 kk = *(const bf16x8*)(kp + u * 8);
            bf16x8 vvv = *(const bf16x8*)(vp + u * 8);
#pragma unroll
            for (int j = 0; j < 8; ++j) { ka[u * 8 + j] = kk[j]; va[u * 8 + j] = vvv[j]; }
        }
#pragma unroll
        for (int c = 0; c < 32; ++c) {
            KT[c * 264 + t] = ka[c];
            VT[c * 264 + t] = va[c];
        }
    }
    __syncthreads();

    {
        const int c = tid >> 3;
        const int tc = (tid & 7) * 32;
        float ps = 0.f;
#pragma unroll
        for (int u = 0; u < 4; ++u) {
            bf16x8 kk = *(const bf16x8*)(&KT[c * 264 + tc + u * 8]);
#pragma unroll
            for (int j = 0; j < 8; ++j) ps += (float)kk[j];
        }
        spart[c * 8 + (tid & 7)] = ps;
    }
    {
        const int i = wv >> 1, j = wv & 1;
        const int r = lane & 15, q = lane >> 4;
        f32x4 acc = {};
#pragma unroll
        for (int ch = 0; ch < 8; ++ch) {
            bf16x8 af = *(const bf16x8*)(&KT[(i * 16 + r) * 264 + ch * 32 + q * 8]);
            bf16x8 bf_ = *(const bf16x8*)(&VT[(j * 16 + r) * 264 + ch * 32 + q * 8]);
            acc = __builtin_amdgcn_mfma_f32_16x16x32_bf16(af, bf_, acc, 0, 0, 0);
        }
        bf16x4 kv4;
#pragma unroll
        for (int reg = 0; reg < 4; ++reg) kv4[reg] = (bf16_t)acc[reg];
        *(bf16x4*)(&KVT[(j * 16 + r) * 40 + i * 16 + q * 4]) = kv4;
    }
    __syncthreads();
    if (tid < 32) {
        float s = 0.f;
#pragma unroll
        for (int u = 0; u < 8; ++u) s += spart[tid * 8 + u];
        sbuf[tid] = s;
    }
    __syncthreads();

    {
        const int t = tid;
        const bf16_t* qp = QKV + (size_t)(off + t) * 768 + h * 32;
        float z = 0.f;
#pragma unroll
        for (int u = 0; u < 4; ++u) {
            bf16x8 qq = *(const bf16x8*)(qp + u * 8);
#pragma unroll
            for (int j = 0; j < 8; ++j) z += (float)qq[j] * sbuf[u * 8 + j];
        }
        zinv[t] = 1.0f / (z + 1e-3f);
    }
    __syncthreads();

    {
        const int r = lane & 15, q = lane >> 4;
        bf16x8 b0 = *(const bf16x8*)(&KVT[(r) * 40 + q * 8]);
        bf16x8 b1 = *(const bf16x8*)(&KVT[(16 + r) * 40 + q * 8]);
#pragma unroll
        for (int u = 0; u < 4; ++u) {
            const int mi = wv * 4 + u;
            const bf16_t* ap = QKV + (size_t)(off + mi * 16 + r) * 768 + h * 32 + q * 8;
            bf16x8 af = *(const bf16x8*)ap;
            f32x4 acc0 = {}, acc1 = {};
            acc0 = __builtin_amdgcn_mfma_f32_16x16x32_bf16(af, b0, acc0, 0, 0, 0);
            acc1 = __builtin_amdgcn_mfma_f32_16x16x32_bf16(af, b1, acc1, 0, 0, 0);
#pragma unroll
            for (int reg = 0; reg < 4; ++reg) {
                const int row = mi * 16 + q * 4 + reg;
                const float zi = zinv[row];
                bf16_t* yp = Y + (size_t)(off + row) * 256 + h * 32;
                yp[r]      = (bf16_t)(acc0[reg] * zi);
                yp[16 + r] = (bf16_t)(acc1[reg] * zi);
            }
        }
    }
}

extern "C" void kernel_launch(void* const* d_in, const int* in_sizes, int n_in,
                              void* d_out, int out_size, void* d_ws, size_t ws_size,
                              hipStream_t stream) {
    const float* x      = (const float*)d_in[0];   // [32768, 256] fp32
    const float* w_qkv  = (const float*)d_in[1];   // [768, 256]   fp32
    const float* w_proj = (const float*)d_in[2];   // [256, 256]   fp32
    const float* b_proj = (const float*)d_in[3];   // [256]        fp32
    const int*   offs   = (const int*)d_in[4];
    const int*   cnts   = (const int*)d_in[5];

    const int NX = in_sizes[0];
    const int M  = NX / KDIM;            // 32768 tokens

    char* ws = (char*)d_ws;
    bf16_t* QKV = (bf16_t*)ws;                    // 50331648 B
    bf16_t* Y   = (bf16_t*)(ws + 50331648);       // 16777216 B
    float*  out = (float*)d_out;

    // opt into >64KB dynamic LDS (host-side attribute set; not a stream op)
    static bool attr_done = false;
    if (!attr_done) {
        hipFuncSetAttribute((const void*)gemm_os<1, 0>,
                            hipFuncAttributeMaxDynamicSharedMemorySize, GEMM_LDS_BYTES);
        hipFuncSetAttribute((const void*)gemm_os<0, 1>,
                            hipFuncAttributeMaxDynamicSharedMemorySize, GEMM_LDS_BYTES);
        attr_done = true;
    }

    // 1) QKV = x @ w_qkv^T (fp32->bf16 in staging), relu cols<512
    gemm_os<1, 0><<<dim3(M / 128, 768 / 128), 256, GEMM_LDS_BYTES, stream>>>(
        (const void*)x, w_qkv, (void*)QKV, 768, nullptr, 512);

    // 2+3) fused per-(window,head) KV state + normalize -> Y bf16
    kvy_kernel<<<dim3(NWIN, 8), 256, 0, stream>>>(QKV, offs, cnts, Y);

    // 4) out = Y @ w_proj^T + b_proj, fp32 out
    gemm_os<0, 1><<<dim3(M / 128, 256 / 128), 256, GEMM_LDS_BYTES, stream>>>(
        (const void*)Y, w_proj, (void*)out, 256, b_proj, 0);
}

// Round 8
// 138.599 us; speedup vs baseline: 1.5320x; 1.5320x over previous
//
#include <hip/hip_runtime.h>

typedef __bf16 bf16_t;
typedef bf16_t bf16x8 __attribute__((ext_vector_type(8)));
typedef bf16_t bf16x4 __attribute__((ext_vector_type(4)));
typedef float f32x4 __attribute__((ext_vector_type(4)));

#define M_TOK 32768
#define NWIN 128
#define WIN  256

typedef __attribute__((address_space(3))) void* as3p;
typedef const __attribute__((address_space(1))) void* as1p;

__device__ __forceinline__ void gll16(const void* g, void* l) {
    __builtin_amdgcn_global_load_lds((as1p)g, (as3p)l, 16, 0, 0);
}

__device__ __forceinline__ bf16x8 cvt8(f32x4 a, f32x4 b) {
    bf16x8 o;
    o[0] = (bf16_t)a[0]; o[1] = (bf16_t)a[1]; o[2] = (bf16_t)a[2]; o[3] = (bf16_t)a[3];
    o[4] = (bf16_t)b[0]; o[5] = (bf16_t)b[1]; o[6] = (bf16_t)b[2]; o[7] = (bf16_t)b[3];
    return o;
}

// tiny fp32->bf16 weight convert (w_qkv 196608 + w_proj 65536 elems)
__global__ __launch_bounds__(256) void wconv(
    const float* __restrict__ wq, const float* __restrict__ wp,
    bf16_t* __restrict__ wqb, bf16_t* __restrict__ wpb)
{
    int i4 = (blockIdx.x * 256 + threadIdx.x) * 4;
    const float* s; bf16_t* dst; int idx;
    if (i4 < 196608) { s = wq; dst = wqb; idx = i4; }
    else             { s = wp; dst = wpb; idx = i4 - 196608; }
    f32x4 v = *(const f32x4*)(s + idx);
    bf16x4 o;
    o[0] = (bf16_t)v[0]; o[1] = (bf16_t)v[1]; o[2] = (bf16_t)v[2]; o[3] = (bf16_t)v[3];
    *(bf16x4*)(dst + idx) = o;
}

// GEMM1: QKV = relu_qk(X @ Wqkv^T), X fp32 [32768,256], W bf16 [768,256].
// Output layout: QKV[nblk][tok][32] with nblk = n>>5 (0..7 q, 8..15 k, 16..23 v).
// m97-style: global_load_lds staging (A as fp32), BK=64, swapped-operand epilogue.
__global__ __launch_bounds__(256) void gemm1_qkv(
    const float* __restrict__ X,
    const bf16_t* __restrict__ Wb,
    bf16_t* __restrict__ QKV)
{
    __shared__ float  As[4][128][16];   // 4 panels of 16 fp32-k, 64B rows
    __shared__ bf16_t Bs[2][128][32];   // 2 panels of 32 bf16-k, 64B rows

    const int tid = threadIdx.x;
    const int lane = tid & 63;
    const int wv = tid >> 6;
    const int wm = wv >> 1, wn = wv & 1;
    // supertile swizzle: 8 m-blocks x 6 n-blocks share A/B panels in L2
    const int id = blockIdx.x;
    const int sg = id / 48, wsub = id % 48;
    const int m0 = (sg * 8 + (wsub & 7)) * 128;
    const int n0 = (wsub >> 3) * 128;
    const int r = lane & 15, q = lane >> 4;
    const int srow = lane >> 2;

    f32x4 acc[4][4] = {};

    for (int kc = 0; kc < 256; kc += 64) {
        // stage A (fp32): 4 panels x 2 insts/wave
#pragma unroll
        for (int p = 0; p < 4; ++p)
#pragma unroll
            for (int g = 0; g < 2; ++g) {
                const int rb = wv * 32 + g * 16;
                gll16(X + (size_t)(m0 + rb + srow) * 256 + kc + p * 16 + (lane & 3) * 4,
                      &As[p][rb][0]);
            }
        // stage B (bf16): 2 panels x 2 insts/wave
#pragma unroll
        for (int p = 0; p < 2; ++p)
#pragma unroll
            for (int g = 0; g < 2; ++g) {
                const int rb = wv * 32 + g * 16;
                gll16(Wb + (size_t)(n0 + rb + srow) * 256 + kc + p * 32 + (lane & 3) * 8,
                      &Bs[p][rb][0]);
            }
        __syncthreads();

#pragma unroll
        for (int kk = 0; kk < 64; kk += 32) {
            const int kq = kk + q * 8;
            const int pA = kq >> 4, offA = kq & 15;
            const int pB = kk >> 5;
            bf16x8 a[4], b[4];
#pragma unroll
            for (int i = 0; i < 4; ++i) {
                f32x4 lo = *(const f32x4*)&As[pA][wm * 64 + i * 16 + r][offA];
                f32x4 hi = *(const f32x4*)&As[pA][wm * 64 + i * 16 + r][offA + 4];
                a[i] = cvt8(lo, hi);
            }
#pragma unroll
            for (int j = 0; j < 4; ++j)
                b[j] = *(const bf16x8*)&Bs[pB][wn * 64 + j * 16 + r][q * 8];
#pragma unroll
            for (int i = 0; i < 4; ++i)
#pragma unroll
                for (int j = 0; j < 4; ++j)   // swapped: col-field->m(r), row-field->n(q*4+reg)
                    acc[i][j] = __builtin_amdgcn_mfma_f32_16x16x32_bf16(b[j], a[i], acc[i][j], 0, 0, 0);
        }
        __syncthreads();
    }

#pragma unroll
    for (int i = 0; i < 4; ++i) {
        const int rowg = m0 + wm * 64 + i * 16 + r;
#pragma unroll
        for (int j = 0; j < 4; ++j) {
            const int nb = n0 + wn * 64 + j * 16 + q * 4;
            const int nblk = nb >> 5, d = nb & 31;
            bf16x4 o;
#pragma unroll
            for (int reg = 0; reg < 4; ++reg) {
                float v = acc[i][j][reg];
                if (nblk < 16) v = fmaxf(v, 0.0f);   // relu on q,k (n<512)
                o[reg] = (bf16_t)v;
            }
            *(bf16x4*)&QKV[((size_t)nblk * M_TOK + rowg) * 32 + d] = o;
        }
    }
}

// GEMM2: Out = Y @ Wproj^T + b, Y bf16 [32768,256] row-major, Out fp32.
__global__ __launch_bounds__(256) void gemm2_proj(
    const bf16_t* __restrict__ Y,
    const bf16_t* __restrict__ Wb,
    const float* __restrict__ bias,
    float* __restrict__ Out)
{
    __shared__ bf16_t As[2][128][32];
    __shared__ bf16_t Bs[2][128][32];

    const int tid = threadIdx.x;
    const int lane = tid & 63;
    const int wv = tid >> 6;
    const int wm = wv >> 1, wn = wv & 1;
    const int id = blockIdx.x;
    const int sg = id / 32, wsub = id % 32;
    const int m0 = (sg * 16 + (wsub & 15)) * 128;
    const int n0 = (wsub >> 4) * 128;
    const int r = lane & 15, q = lane >> 4;
    const int srow = lane >> 2;

    f32x4 acc[4][4] = {};

    for (int kc = 0; kc < 256; kc += 64) {
#pragma unroll
        for (int p = 0; p < 2; ++p)
#pragma unroll
            for (int g = 0; g < 2; ++g) {
                const int rb = wv * 32 + g * 16;
                gll16(Y + (size_t)(m0 + rb + srow) * 256 + kc + p * 32 + (lane & 3) * 8,
                      &As[p][rb][0]);
                gll16(Wb + (size_t)(n0 + rb + srow) * 256 + kc + p * 32 + (lane & 3) * 8,
                      &Bs[p][rb][0]);
            }
        __syncthreads();

#pragma unroll
        for (int kk = 0; kk < 64; kk += 32) {
            const int pB = kk >> 5;
            bf16x8 a[4], b[4];
#pragma unroll
            for (int i = 0; i < 4; ++i)
                a[i] = *(const bf16x8*)&As[pB][wm * 64 + i * 16 + r][q * 8];
#pragma unroll
            for (int j = 0; j < 4; ++j)
                b[j] = *(const bf16x8*)&Bs[pB][wn * 64 + j * 16 + r][q * 8];
#pragma unroll
            for (int i = 0; i < 4; ++i)
#pragma unroll
                for (int j = 0; j < 4; ++j)
                    acc[i][j] = __builtin_amdgcn_mfma_f32_16x16x32_bf16(b[j], a[i], acc[i][j], 0, 0, 0);
        }
        __syncthreads();
    }

#pragma unroll
    for (int i = 0; i < 4; ++i) {
        const int rowg = m0 + wm * 64 + i * 16 + r;
#pragma unroll
        for (int j = 0; j < 4; ++j) {
            const int nb = n0 + wn * 64 + j * 16 + q * 4;
            f32x4 bi = *(const f32x4*)(bias + nb);
            f32x4 o;
#pragma unroll
            for (int reg = 0; reg < 4; ++reg) o[reg] = acc[i][j][reg] + bi[reg];
            *(f32x4*)&Out[(size_t)rowg * 256 + nb] = o;
        }
    }
}

// Fused per-(window,head) linear attention on blocked QKV layout.
__global__ __launch_bounds__(256) void kvy_kernel(
    const bf16_t* __restrict__ QKV,   // [24][32768][32]
    const int* __restrict__ offsets,
    const int* __restrict__ counts,
    bf16_t* __restrict__ Y)           // [32768,256] row-major
{
    const int w = blockIdx.x;
    const int h = blockIdx.y;
    const int is64 = (counts[1] == 0) ? 1 : 0;
    const int off = offsets[w << is64];
    const int tid = threadIdx.x;
    const int lane = tid & 63;
    const int wv = tid >> 6;

    __shared__ __align__(16) bf16_t KT[32 * 264];   // KT[c][t]
    __shared__ __align__(16) bf16_t VT[32 * 264];   // VT[d][t]
    __shared__ __align__(16) bf16_t KVT[32 * 40];   // KVT[d][c]
    __shared__ float sbuf[32];
    __shared__ float spart[32 * 8];
    __shared__ float zinv[WIN];

    // P0: stage K,V transposed (thread = token); fully coalesced 64B/token reads
    {
        const int t = tid;
        const bf16_t* kp = QKV + ((size_t)(8 + h) * M_TOK + off + t) * 32;
        const bf16_t* vp = QKV + ((size_t)(16 + h) * M_TOK + off + t) * 32;
        bf16_t ka[32], va[32];
#pragma unroll
        for (int u = 0; u < 4; ++u) {
            bf16x8 kk = *(const bf16x8*)(kp + u * 8);
            bf16x8 vvv = *(const bf16x8*)(vp + u * 8);
#pragma unroll
            for (int j = 0; j < 8; ++j) { ka[u * 8 + j] = kk[j]; va[u * 8 + j] = vvv[j]; }
        }
#pragma unroll
        for (int c = 0; c < 32; ++c) {
            KT[c * 264 + t] = ka[c];
            VT[c * 264 + t] = va[c];
        }
    }
    __syncthreads();

    // P1a: s partials
    {
        const int c = tid >> 3;
        const int tc = (tid & 7) * 32;
        float ps = 0.f;
#pragma unroll
        for (int u = 0; u < 4; ++u) {
            bf16x8 kk = *(const bf16x8*)(&KT[c * 264 + tc + u * 8]);
#pragma unroll
            for (int j = 0; j < 8; ++j) ps += (float)kk[j];
        }
        spart[c * 8 + (tid & 7)] = ps;
    }
    // P1b: KV = K^T V via MFMA (col-field->d, row-field->c); store KVT[d][c]
    {
        const int i = wv >> 1, j = wv & 1;
        const int r = lane & 15, q = lane >> 4;
        f32x4 acc = {};
#pragma unroll
        for (int ch = 0; ch < 8; ++ch) {
            bf16x8 af = *(const bf16x8*)(&KT[(i * 16 + r) * 264 + ch * 32 + q * 8]);
            bf16x8 bf_ = *(const bf16x8*)(&VT[(j * 16 + r) * 264 + ch * 32 + q * 8]);
            acc = __builtin_amdgcn_mfma_f32_16x16x32_bf16(af, bf_, acc, 0, 0, 0);
        }
        bf16x4 kv4;
#pragma unroll
        for (int reg = 0; reg < 4; ++reg) kv4[reg] = (bf16_t)acc[reg];
        *(bf16x4*)(&KVT[(j * 16 + r) * 40 + i * 16 + q * 4]) = kv4;
    }
    __syncthreads();
    if (tid < 32) {
        float s = 0.f;
#pragma unroll
        for (int u = 0; u < 8; ++u) s += spart[tid * 8 + u];
        sbuf[tid] = s;
    }
    __syncthreads();

    // P2: zinv[t]
    {
        const int t = tid;
        const bf16_t* qp = QKV + ((size_t)h * M_TOK + off + t) * 32;
        float z = 0.f;
#pragma unroll
        for (int u = 0; u < 4; ++u) {
            bf16x8 qq = *(const bf16x8*)(qp + u * 8);
#pragma unroll
            for (int j = 0; j < 8; ++j) z += (float)qq[j] * sbuf[u * 8 + j];
        }
        zinv[t] = 1.0f / (z + 1e-3f);
    }
    __syncthreads();

    // P3: y = (Q.KV)*zinv via swapped MFMA (col-field->t, row-field->d): bf16x4 stores
    {
        const int r = lane & 15, q = lane >> 4;
        bf16x8 b0 = *(const bf16x8*)(&KVT[(r) * 40 + q * 8]);        // d=r   (j=0)
        bf16x8 b1 = *(const bf16x8*)(&KVT[(16 + r) * 40 + q * 8]);   // d=16+r(j=1)
#pragma unroll
        for (int u = 0; u < 4; ++u) {
            const int mi = wv * 4 + u;
            const bf16_t* ap = QKV + ((size_t)h * M_TOK + off + mi * 16 + r) * 32 + q * 8;
            bf16x8 af = *(const bf16x8*)ap;
            f32x4 acc0 = {}, acc1 = {};
            acc0 = __builtin_amdgcn_mfma_f32_16x16x32_bf16(b0, af, acc0, 0, 0, 0);
            acc1 = __builtin_amdgcn_mfma_f32_16x16x32_bf16(b1, af, acc1, 0, 0, 0);
            const int tkn = mi * 16 + r;
            const float zi = zinv[tkn];
            bf16_t* yp = Y + (size_t)(off + tkn) * 256 + h * 32;
            bf16x4 o0, o1;
#pragma unroll
            for (int reg = 0; reg < 4; ++reg) {
                o0[reg] = (bf16_t)(acc0[reg] * zi);
                o1[reg] = (bf16_t)(acc1[reg] * zi);
            }
            *(bf16x4*)(yp + q * 4) = o0;
            *(bf16x4*)(yp + 16 + q * 4) = o1;
        }
    }
}

extern "C" void kernel_launch(void* const* d_in, const int* in_sizes, int n_in,
                              void* d_out, int out_size, void* d_ws, size_t ws_size,
                              hipStream_t stream) {
    const float* x      = (const float*)d_in[0];
    const float* w_qkv  = (const float*)d_in[1];
    const float* w_proj = (const float*)d_in[2];
    const float* b_proj = (const float*)d_in[3];
    const int*   offs   = (const int*)d_in[4];
    const int*   cnts   = (const int*)d_in[5];

    char* ws = (char*)d_ws;
    bf16_t* QKV = (bf16_t*)ws;                    // 24*32768*32*2 = 50331648 B
    bf16_t* Y   = (bf16_t*)(ws + 50331648);       // 16777216 B
    bf16_t* Wqb = (bf16_t*)(ws + 67108864);       //   393216 B
    bf16_t* Wpb = (bf16_t*)(ws + 67502080);       //   131072 B
    float*  out = (float*)d_out;

    // 0) weights fp32 -> bf16 (0.5 MB out)
    wconv<<<256, 256, 0, stream>>>(w_qkv, w_proj, Wqb, Wpb);

    // 1) QKV gemm (blocked output layout)
    gemm1_qkv<<<1536, 256, 0, stream>>>(x, Wqb, QKV);

    // 2+3) fused per-(window,head) KV + normalize
    kvy_kernel<<<dim3(NWIN, 8), 256, 0, stream>>>(QKV, offs, cnts, Y);

    // 4) proj gemm, fp32 out
    gemm2_proj<<<512, 256, 0, stream>>>(Y, Wpb, b_proj, out);
}